// Round 6
// baseline (202.136 us; speedup 1.0000x reference)
//
#include <hip/hip_runtime.h>
#include <cstdint>
#include <cstddef>

#define TOKENS 8192
#define DIN    4096
#define DOUT   4096

typedef int int4v  __attribute__((ext_vector_type(4)));
typedef int int16v __attribute__((ext_vector_type(16)));

// ---------------------------------------------------------------------------
// Kernel 1: per-token dynamic quantization (unchanged, near HBM-bound).
// ---------------------------------------------------------------------------
__global__ __launch_bounds__(256) void quant_rows(const float* __restrict__ x,
                                                  int* __restrict__ xq,
                                                  float* __restrict__ ascale,
                                                  int* __restrict__ rsum) {
  const int row = blockIdx.x;
  const int t = threadIdx.x;
  const float4* xr = (const float4*)(x + (size_t)row * DIN);
  float4 v[4];
#pragma unroll
  for (int i = 0; i < 4; ++i) v[i] = xr[i * 256 + t];

  float m = 0.f;
#pragma unroll
  for (int i = 0; i < 4; ++i) {
    m = fmaxf(m, fabsf(v[i].x)); m = fmaxf(m, fabsf(v[i].y));
    m = fmaxf(m, fabsf(v[i].z)); m = fmaxf(m, fabsf(v[i].w));
  }
#pragma unroll
  for (int off = 32; off; off >>= 1) m = fmaxf(m, __shfl_xor(m, off));

  __shared__ float wmax[4];
  __shared__ int   wsum[4];
  const int lane = t & 63, wid = t >> 6;
  if (lane == 0) wmax[wid] = m;
  __syncthreads();
  m = fmaxf(fmaxf(wmax[0], wmax[1]), fmaxf(wmax[2], wmax[3]));

  const float s = m * (1.0f / 127.0f);
  const float sdiv = (m > 0.f) ? s : 1.0f;

  int ssum = 0;
#pragma unroll
  for (int i = 0; i < 4; ++i) {
    float q;
    q = fminf(fmaxf(rintf(v[i].x / sdiv), -127.f), 127.f); const int b0 = (int)q;
    q = fminf(fmaxf(rintf(v[i].y / sdiv), -127.f), 127.f); const int b1 = (int)q;
    q = fminf(fmaxf(rintf(v[i].z / sdiv), -127.f), 127.f); const int b2 = (int)q;
    q = fminf(fmaxf(rintf(v[i].w / sdiv), -127.f), 127.f); const int b3 = (int)q;
    ssum += b0 + b1 + b2 + b3;
    xq[(size_t)row * 1024 + i * 256 + t] =
        (b0 & 255) | ((b1 & 255) << 8) | ((b2 & 255) << 16) | ((b3 & 255) << 24);
  }
#pragma unroll
  for (int off = 32; off; off >>= 1) ssum += __shfl_xor(ssum, off);
  if (lane == 0) wsum[wid] = ssum;
  __syncthreads();
  if (t == 0) {
    rsum[row]   = wsum[0] + wsum[1] + wsum[2] + wsum[3];
    ascale[row] = s;
  }
}

// ---------------------------------------------------------------------------
// Kernel 2: weight int32 -> packed int8 (unchanged).
// ---------------------------------------------------------------------------
__global__ __launch_bounds__(256) void wconv(const int* __restrict__ w,
                                             int* __restrict__ w8) {
  const int idx = blockIdx.x * 256 + threadIdx.x;
  const int4 v = ((const int4*)w)[idx];
  w8[idx] = (v.x & 255) | ((v.y & 255) << 8) | ((v.z & 255) << 16) | ((v.w & 255) << 24);
}

// ---------------------------------------------------------------------------
// Kernel 3: i8 GEMM, 256x256 tile, 1-barrier/tile, NOTHING-after-barrier.
//  - 512 thr = 8 waves (2M x 4N), per-wave 128x64 C, mfma_i32_32x32x32_i8
//  - LDS 128 KiB: 4-buffer ring; prefetch depth 3
//  - vmcnt(4) per tile => at end of tile T, buffers T+1 AND T+2 are visible.
//    Invariant lets tile T read k0 of T+1 BEFORE its end barrier, under the
//    MFMA-k1 shadow. Post-barrier MFMA starts immediately on loaded regs;
//    the serial path per tile is just {MFMA k0 | MFMA k1 | barrier}.
//  - T2 involution swizzle (bits 4-5) as round 5 (verified passing).
// ---------------------------------------------------------------------------
__device__ __forceinline__ void gload_lds16(const char* g, char* l) {
  __builtin_amdgcn_global_load_lds(
      (const __attribute__((address_space(1))) void*)g,
      (__attribute__((address_space(3))) void*)l, 16, 0, 0);
}

#define MFMA8(AV, BV)                                                         \
  __builtin_amdgcn_s_setprio(1);                                              \
  _Pragma("unroll")                                                           \
  for (int mi = 0; mi < 4; ++mi)                                              \
    _Pragma("unroll")                                                         \
    for (int ni = 0; ni < 2; ++ni)                                            \
      acc[mi][ni] = __builtin_amdgcn_mfma_i32_32x32x32_i8(                    \
          AV[mi], BV[ni], acc[mi][ni], 0, 0, 0);                              \
  __builtin_amdgcn_s_setprio(0);

// Tile body: stage T+3 | read k1(T) | MFMA k0 | read k0(T+1) | MFMA k1 |
//            [vmcnt(N) lgkm(0) barrier]
#define TILE_BODY(T_, STAGE_, VMN_, NEXT_)                                    \
  do {                                                                        \
    const char* Lb = lds + ((T_) & 3) * 32768;                                \
    char* Wb = lds + (((T_) + 3) & 3) * 32768;                                \
    if (STAGE_) {                                                             \
      const size_t ko = (size_t)((T_) + 3) * 64;                              \
      gload_lds16(gA0 + ko, Wb + ldst);                                       \
      gload_lds16(gA1 + ko, Wb + 8192 + ldst);                                \
      gload_lds16(gB0 + ko, Wb + 16384 + ldst);                               \
      gload_lds16(gB1 + ko, Wb + 24576 + ldst);                               \
    }                                                                         \
    _Pragma("unroll")                                                         \
    for (int mi = 0; mi < 4; ++mi)                                            \
      aB[mi] = *(const int4v*)(Lb + aoff1 + mi * 2048);                       \
    _Pragma("unroll")                                                         \
    for (int ni = 0; ni < 2; ++ni)                                            \
      bB[ni] = *(const int4v*)(Lb + boff1 + ni * 2048);                       \
    MFMA8(aA, bA)                                                             \
    if (NEXT_) {                                                              \
      const char* Ln = lds + (((T_) + 1) & 3) * 32768;                        \
      _Pragma("unroll")                                                       \
      for (int mi = 0; mi < 4; ++mi)                                          \
        aA[mi] = *(const int4v*)(Ln + aoff0 + mi * 2048);                     \
      _Pragma("unroll")                                                       \
      for (int ni = 0; ni < 2; ++ni)                                          \
        bA[ni] = *(const int4v*)(Ln + boff0 + ni * 2048);                     \
    }                                                                         \
    MFMA8(aB, bB)                                                             \
    if ((VMN_) >= 0) {                                                        \
      if ((VMN_) == 4)      asm volatile("s_waitcnt vmcnt(4)" ::: "memory");  \
      else if ((VMN_) == 0) asm volatile("s_waitcnt vmcnt(0)" ::: "memory");  \
      asm volatile("s_waitcnt lgkmcnt(0)" ::: "memory");                      \
      __builtin_amdgcn_s_barrier();                                           \
    }                                                                         \
  } while (0)

__global__ __launch_bounds__(512, 2) void gemm_i8(
    const char* __restrict__ xq, const char* __restrict__ w8,
    const float* __restrict__ ascale, const int* __restrict__ rsum,
    const float* __restrict__ wscale, const float* __restrict__ woff,
    const float* __restrict__ bias, float* __restrict__ y) {

  // 4 ring buffers x [Aunit0|Aunit1|Bunit0|Bunit1] x 8 KiB = 128 KiB
  __shared__ __align__(16) char lds[131072];

  const int bid = blockIdx.x;
  const int tm = bid >> 4;            // 32 M-tiles
  const int tn = bid & 15;            // 16 N-tiles
  const int t = threadIdx.x;          // 0..511
  const int lane = t & 63, wid = t >> 6;
  const int wmI = wid >> 2;           // 0..1 (M)
  const int wnI = wid & 3;            // 0..3 (N)

  // ---- staging source: involution P(L)=L^(((L>>7)&3)<<4) applied to L=t*16:
  const int srow = t >> 2;                              // 0..127 within unit
  const int scol = ((t & 3) ^ ((t >> 3) & 3)) * 16;     // 0/16/32/48

  const char* gA0 = xq + (size_t)(tm * 256 + srow) * DIN + scol;
  const char* gA1 = gA0 + (size_t)128 * DIN;
  const char* gB0 = w8 + (size_t)(tn * 256 + srow) * DIN + scol;
  const char* gB1 = gB0 + (size_t)128 * DIN;
  const int ldst = t * 16;                              // LINEAR LDS dest

  // ---- fragment read offsets (same involution; mask = row bits 1-2) ----
  const int mask  = ((lane >> 1) & 3) << 4;
  const int chunk = (lane >> 5) * 16;                   // k-chunk within 64B row
  const int aoff0 = wmI * 8192 + (lane & 31) * 64 + ((chunk +  0) ^ mask);
  const int aoff1 = wmI * 8192 + (lane & 31) * 64 + ((chunk + 32) ^ mask);
  const int bbase = (2 + (wnI >> 1)) * 8192 + (wnI & 1) * 4096 + (lane & 31) * 64;
  const int boff0 = bbase + ((chunk +  0) ^ mask);
  const int boff1 = bbase + ((chunk + 32) ^ mask);

  int16v acc[4][2];
#pragma unroll
  for (int mi = 0; mi < 4; ++mi)
#pragma unroll
    for (int ni = 0; ni < 2; ++ni)
#pragma unroll
      for (int rg = 0; rg < 16; ++rg) acc[mi][ni][rg] = 0;

  int4v aA[4], bA[2], aB[4], bB[2];

  // ---- prologue: stage K-tiles 0,1,2; make buffers 0 AND 1 visible ----
#pragma unroll
  for (int p = 0; p < 3; ++p) {
    char* Wb = lds + p * 32768;
    gload_lds16(gA0 + p * 64, Wb + ldst);
    gload_lds16(gA1 + p * 64, Wb + 8192 + ldst);
    gload_lds16(gB0 + p * 64, Wb + 16384 + ldst);
    gload_lds16(gB1 + p * 64, Wb + 24576 + ldst);
  }
  asm volatile("s_waitcnt vmcnt(4)" ::: "memory");   // tiles 0,1 landed
  __builtin_amdgcn_s_barrier();
#pragma unroll
  for (int mi = 0; mi < 4; ++mi) aA[mi] = *(const int4v*)(lds + aoff0 + mi * 2048);
#pragma unroll
  for (int ni = 0; ni < 2; ++ni) bA[ni] = *(const int4v*)(lds + boff0 + ni * 2048);

  // ---- main loop: 64 K-tiles; invariant: at tile T, buffers T..T+1 visible;
  //      end-of-T vmcnt(4) drains buffer T+2 just in time for tile T+1 ----
  for (int T = 0; T < 61; ++T) TILE_BODY(T, 1, 4, 1);
  TILE_BODY(61, 0, 0, 1);    // drain buffer 63
  TILE_BODY(62, 0, -1, 1);   // no staging left -> no barrier needed
  TILE_BODY(63, 0, -1, 0);

  // ---- epilogue: zp-correction + dequant + bias ----
  // C/D 32x32: col = lane&31, row = (rg&3) + 8*(rg>>2) + 4*(lane>>5)
  const int rb0 = tm * 256 + wmI * 128 + 4 * (lane >> 5);
  const int cb0 = tn * 256 + wnI * 64 + (lane & 31);
  const float ws0 = wscale[cb0],      ws1 = wscale[cb0 + 32];
  const float wo0 = woff[cb0],        wo1 = woff[cb0 + 32];
  const float bi0 = bias[cb0],        bi1 = bias[cb0 + 32];
#pragma unroll
  for (int mi = 0; mi < 4; ++mi) {
#pragma unroll
    for (int rg = 0; rg < 16; ++rg) {
      const int r = rb0 + mi * 32 + (rg & 3) + 8 * (rg >> 2);
      const float as_ = ascale[r];
      const float rs_ = (float)rsum[r];
      y[(size_t)r * DOUT + cb0]      = ((float)acc[mi][0][rg] + rs_ * wo0) * (as_ * ws0) + bi0;
      y[(size_t)r * DOUT + cb0 + 32] = ((float)acc[mi][1][rg] + rs_ * wo1) * (as_ * ws1) + bi1;
    }
  }
}

// ---------------------------------------------------------------------------
extern "C" void kernel_launch(void* const* d_in, const int* in_sizes, int n_in,
                              void* d_out, int out_size, void* d_ws, size_t ws_size,
                              hipStream_t stream) {
  const float* x      = (const float*)d_in[0];
  const int*   w      = (const int*)  d_in[1];
  const float* wscale = (const float*)d_in[2];
  const float* woff   = (const float*)d_in[3];
  const float* bias   = (const float*)d_in[4];
  float* y = (float*)d_out;

  char* ws = (char*)d_ws;
  char*  xq     = ws;                                 // 33,554,432 B
  char*  w8     = ws + (size_t)TOKENS * DIN;          // 16,777,216 B
  float* ascale = (float*)(w8 + (size_t)DOUT * DIN);  // 32,768 B
  int*   rsum   = (int*)(ascale + TOKENS);            // 32,768 B

  hipLaunchKernelGGL(quant_rows, dim3(TOKENS), dim3(256), 0, stream,
                     x, (int*)xq, ascale, rsum);
  hipLaunchKernelGGL(wconv, dim3((DOUT * DIN / 4) / 256), dim3(256), 0, stream,
                     w, (int*)w8);
  hipLaunchKernelGGL(gemm_i8, dim3((TOKENS / 256) * (DOUT / 256)), dim3(512), 0, stream,
                     xq, w8, ascale, rsum, wscale, woff, bias, y);
}

// Round 7
// 201.640 us; speedup vs baseline: 1.0025x; 1.0025x over previous
//
#include <hip/hip_runtime.h>
#include <cstdint>
#include <cstddef>

#define TOKENS 8192
#define DIN    4096
#define DOUT   4096

typedef int int4v  __attribute__((ext_vector_type(4)));
typedef int int16v __attribute__((ext_vector_type(16)));

// ---------------------------------------------------------------------------
// Kernel 1: per-token dynamic quantization (unchanged, near HBM-bound).
// ---------------------------------------------------------------------------
__global__ __launch_bounds__(256) void quant_rows(const float* __restrict__ x,
                                                  int* __restrict__ xq,
                                                  float* __restrict__ ascale,
                                                  int* __restrict__ rsum) {
  const int row = blockIdx.x;
  const int t = threadIdx.x;
  const float4* xr = (const float4*)(x + (size_t)row * DIN);
  float4 v[4];
#pragma unroll
  for (int i = 0; i < 4; ++i) v[i] = xr[i * 256 + t];

  float m = 0.f;
#pragma unroll
  for (int i = 0; i < 4; ++i) {
    m = fmaxf(m, fabsf(v[i].x)); m = fmaxf(m, fabsf(v[i].y));
    m = fmaxf(m, fabsf(v[i].z)); m = fmaxf(m, fabsf(v[i].w));
  }
#pragma unroll
  for (int off = 32; off; off >>= 1) m = fmaxf(m, __shfl_xor(m, off));

  __shared__ float wmax[4];
  __shared__ int   wsum[4];
  const int lane = t & 63, wid = t >> 6;
  if (lane == 0) wmax[wid] = m;
  __syncthreads();
  m = fmaxf(fmaxf(wmax[0], wmax[1]), fmaxf(wmax[2], wmax[3]));

  const float s = m * (1.0f / 127.0f);
  const float sdiv = (m > 0.f) ? s : 1.0f;

  int ssum = 0;
#pragma unroll
  for (int i = 0; i < 4; ++i) {
    float q;
    q = fminf(fmaxf(rintf(v[i].x / sdiv), -127.f), 127.f); const int b0 = (int)q;
    q = fminf(fmaxf(rintf(v[i].y / sdiv), -127.f), 127.f); const int b1 = (int)q;
    q = fminf(fmaxf(rintf(v[i].z / sdiv), -127.f), 127.f); const int b2 = (int)q;
    q = fminf(fmaxf(rintf(v[i].w / sdiv), -127.f), 127.f); const int b3 = (int)q;
    ssum += b0 + b1 + b2 + b3;
    xq[(size_t)row * 1024 + i * 256 + t] =
        (b0 & 255) | ((b1 & 255) << 8) | ((b2 & 255) << 16) | ((b3 & 255) << 24);
  }
#pragma unroll
  for (int off = 32; off; off >>= 1) ssum += __shfl_xor(ssum, off);
  if (lane == 0) wsum[wid] = ssum;
  __syncthreads();
  if (t == 0) {
    rsum[row]   = wsum[0] + wsum[1] + wsum[2] + wsum[3];
    ascale[row] = s;
  }
}

// ---------------------------------------------------------------------------
// Kernel 2: weight int32 -> packed int8 (unchanged).
// ---------------------------------------------------------------------------
__global__ __launch_bounds__(256) void wconv(const int* __restrict__ w,
                                             int* __restrict__ w8) {
  const int idx = blockIdx.x * 256 + threadIdx.x;
  const int4 v = ((const int4*)w)[idx];
  w8[idx] = (v.x & 255) | ((v.y & 255) << 8) | ((v.z & 255) << 16) | ((v.w & 255) << 24);
}

// ---------------------------------------------------------------------------
// Kernel 3: i8 GEMM, 256x256 tile, 1-barrier/tile pipelined schedule.
//  - 512 thr = 8 waves (2M x 4N), per-wave 128x64 C, mfma_i32_32x32x32_i8
//  - LDS 128 KiB: 4-buffer ring; prefetch depth 3; tile end = vmcnt(4)+barrier
//    ONLY (no lgkm drain: all buffer-T reads are register-consumed by MFMAs
//    before the barrier, so the compiler's own lgkm waits already guarantee
//    completion; barrier makes it block-wide before T+1's stage overwrites).
//  - 3-bit involution swizzle P(F) = F ^ (((F>>7)&3)<<4) ^ (((F>>10)&1)<<6):
//    targets bits 4-6, sources bits 7,8,10 (disjoint -> self-inverse).
//    Read mask is a pure lane function (lane bits 1,2,4) so all fragment
//    offsets stay additive in unit/mi strides. Rows r, r+8, r+16 now map to
//    distinct bank-quads -> 2-way (free) instead of 4-way.
//  - no sched_barrier: compiler interleaves ds_reads among MFMAs (keeps the
//    LDS queue fed smoothly instead of post-barrier bursts). setprio kept.
// ---------------------------------------------------------------------------
__device__ __forceinline__ void gload_lds16(const char* g, char* l) {
  __builtin_amdgcn_global_load_lds(
      (const __attribute__((address_space(1))) void*)g,
      (__attribute__((address_space(3))) void*)l, 16, 0, 0);
}

#define MFMA8(AV, BV)                                                         \
  __builtin_amdgcn_s_setprio(1);                                              \
  _Pragma("unroll")                                                           \
  for (int mi = 0; mi < 4; ++mi)                                              \
    _Pragma("unroll")                                                         \
    for (int ni = 0; ni < 2; ++ni)                                            \
      acc[mi][ni] = __builtin_amdgcn_mfma_i32_32x32x32_i8(                    \
          AV[mi], BV[ni], acc[mi][ni], 0, 0, 0);                              \
  __builtin_amdgcn_s_setprio(0);

// Tile body: stage T+3 | read k1(T) | MFMA k0 | read k0(T+1) | MFMA k1 |
//            [vmcnt(N) barrier]
#define TILE_BODY(T_, STAGE_, VMN_, NEXT_)                                    \
  do {                                                                        \
    const char* Lb = lds + ((T_) & 3) * 32768;                                \
    char* Wb = lds + (((T_) + 3) & 3) * 32768;                                \
    if (STAGE_) {                                                             \
      const size_t ko = (size_t)((T_) + 3) * 64;                              \
      gload_lds16(gA0 + ko, Wb + ldst);                                       \
      gload_lds16(gA1 + ko, Wb + 8192 + ldst);                                \
      gload_lds16(gB0 + ko, Wb + 16384 + ldst);                               \
      gload_lds16(gB1 + ko, Wb + 24576 + ldst);                               \
    }                                                                         \
    _Pragma("unroll")                                                         \
    for (int mi = 0; mi < 4; ++mi)                                            \
      aB[mi] = *(const int4v*)(Lb + aoff1 + mi * 2048);                       \
    _Pragma("unroll")                                                         \
    for (int ni = 0; ni < 2; ++ni)                                            \
      bB[ni] = *(const int4v*)(Lb + boff1 + ni * 2048);                       \
    MFMA8(aA, bA)                                                             \
    if (NEXT_) {                                                              \
      const char* Ln = lds + (((T_) + 1) & 3) * 32768;                        \
      _Pragma("unroll")                                                       \
      for (int mi = 0; mi < 4; ++mi)                                          \
        aA[mi] = *(const int4v*)(Ln + aoff0 + mi * 2048);                     \
      _Pragma("unroll")                                                       \
      for (int ni = 0; ni < 2; ++ni)                                          \
        bA[ni] = *(const int4v*)(Ln + boff0 + ni * 2048);                     \
    }                                                                         \
    MFMA8(aB, bB)                                                             \
    if ((VMN_) >= 0) {                                                        \
      if ((VMN_) == 4)      asm volatile("s_waitcnt vmcnt(4)" ::: "memory");  \
      else if ((VMN_) == 0) asm volatile("s_waitcnt vmcnt(0)" ::: "memory");  \
      __builtin_amdgcn_s_barrier();                                           \
    }                                                                         \
  } while (0)

__global__ __launch_bounds__(512, 2) void gemm_i8(
    const char* __restrict__ xq, const char* __restrict__ w8,
    const float* __restrict__ ascale, const int* __restrict__ rsum,
    const float* __restrict__ wscale, const float* __restrict__ woff,
    const float* __restrict__ bias, float* __restrict__ y) {

  // 4 ring buffers x [Aunit0|Aunit1|Bunit0|Bunit1] x 8 KiB = 128 KiB
  __shared__ __align__(16) char lds[131072];

  const int bid = blockIdx.x;
  const int tm = bid >> 4;            // 32 M-tiles
  const int tn = bid & 15;            // 16 N-tiles
  const int t = threadIdx.x;          // 0..511
  const int lane = t & 63, wid = t >> 6;
  const int wmI = wid >> 2;           // 0..1 (M)
  const int wnI = wid & 3;            // 0..3 (N)

  // ---- staging source: S = P(t*16); F bits 7,8,10 = t bits 3,4,6 ----
  const int S = (t * 16) ^ (((t >> 3) & 3) << 4) ^ (((t >> 6) & 1) << 6);
  const int srow = S >> 6;                              // 0..127 within unit
  const int scol = S & 63;

  const char* gA0 = xq + (size_t)(tm * 256 + srow) * DIN + scol;
  const char* gA1 = gA0 + (size_t)128 * DIN;
  const char* gB0 = w8 + (size_t)(tn * 256 + srow) * DIN + scol;
  const char* gB1 = gB0 + (size_t)128 * DIN;
  const int ldst = t * 16;                              // LINEAR LDS dest

  // ---- fragment read offsets: mask = lane bits 1,2 -> bits 4,5; lane bit 4
  //      -> bit 6. Pure lane function; additive in unit/mi strides. ----
  const int mask  = (((lane >> 1) & 3) << 4) ^ (((lane >> 4) & 1) << 6);
  const int arow  = (lane & 31) * 64 + (lane >> 5) * 16;
  const int aoff0 = wmI * 8192 + ((arow +  0) ^ mask);
  const int aoff1 = wmI * 8192 + ((arow + 32) ^ mask);
  const int brow  = (wnI & 1) * 4096 + arow;
  const int boff0 = (2 + (wnI >> 1)) * 8192 + ((brow +  0) ^ mask);
  const int boff1 = (2 + (wnI >> 1)) * 8192 + ((brow + 32) ^ mask);

  int16v acc[4][2];
#pragma unroll
  for (int mi = 0; mi < 4; ++mi)
#pragma unroll
    for (int ni = 0; ni < 2; ++ni)
#pragma unroll
      for (int rg = 0; rg < 16; ++rg) acc[mi][ni][rg] = 0;

  int4v aA[4], bA[2], aB[4], bB[2];

  // ---- prologue: stage K-tiles 0,1,2; make buffers 0 AND 1 visible ----
#pragma unroll
  for (int p = 0; p < 3; ++p) {
    char* Wb = lds + p * 32768;
    gload_lds16(gA0 + p * 64, Wb + ldst);
    gload_lds16(gA1 + p * 64, Wb + 8192 + ldst);
    gload_lds16(gB0 + p * 64, Wb + 16384 + ldst);
    gload_lds16(gB1 + p * 64, Wb + 24576 + ldst);
  }
  asm volatile("s_waitcnt vmcnt(4)" ::: "memory");   // tiles 0,1 landed
  __builtin_amdgcn_s_barrier();
#pragma unroll
  for (int mi = 0; mi < 4; ++mi) aA[mi] = *(const int4v*)(lds + aoff0 + mi * 2048);
#pragma unroll
  for (int ni = 0; ni < 2; ++ni) bA[ni] = *(const int4v*)(lds + boff0 + ni * 2048);

  // ---- main loop: 64 K-tiles; invariant: at tile T, buffers T..T+1 visible;
  //      end-of-T vmcnt(4) drains buffer T+2 just in time for tile T+1 ----
  for (int T = 0; T < 61; ++T) TILE_BODY(T, 1, 4, 1);
  TILE_BODY(61, 0, 0, 1);    // drain buffer 63
  TILE_BODY(62, 0, -1, 1);   // no staging left -> no barrier needed
  TILE_BODY(63, 0, -1, 0);

  // ---- epilogue: zp-correction + dequant + bias ----
  // C/D 32x32: col = lane&31, row = (rg&3) + 8*(rg>>2) + 4*(lane>>5)
  const int rb0 = tm * 256 + wmI * 128 + 4 * (lane >> 5);
  const int cb0 = tn * 256 + wnI * 64 + (lane & 31);
  const float ws0 = wscale[cb0],      ws1 = wscale[cb0 + 32];
  const float wo0 = woff[cb0],        wo1 = woff[cb0 + 32];
  const float bi0 = bias[cb0],        bi1 = bias[cb0 + 32];
#pragma unroll
  for (int mi = 0; mi < 4; ++mi) {
#pragma unroll
    for (int rg = 0; rg < 16; ++rg) {
      const int r = rb0 + mi * 32 + (rg & 3) + 8 * (rg >> 2);
      const float as_ = ascale[r];
      const float rs_ = (float)rsum[r];
      y[(size_t)r * DOUT + cb0]      = ((float)acc[mi][0][rg] + rs_ * wo0) * (as_ * ws0) + bi0;
      y[(size_t)r * DOUT + cb0 + 32] = ((float)acc[mi][1][rg] + rs_ * wo1) * (as_ * ws1) + bi1;
    }
  }
}

// ---------------------------------------------------------------------------
extern "C" void kernel_launch(void* const* d_in, const int* in_sizes, int n_in,
                              void* d_out, int out_size, void* d_ws, size_t ws_size,
                              hipStream_t stream) {
  const float* x      = (const float*)d_in[0];
  const int*   w      = (const int*)  d_in[1];
  const float* wscale = (const float*)d_in[2];
  const float* woff   = (const float*)d_in[3];
  const float* bias   = (const float*)d_in[4];
  float* y = (float*)d_out;

  char* ws = (char*)d_ws;
  char*  xq     = ws;                                 // 33,554,432 B
  char*  w8     = ws + (size_t)TOKENS * DIN;          // 16,777,216 B
  float* ascale = (float*)(w8 + (size_t)DOUT * DIN);  // 32,768 B
  int*   rsum   = (int*)(ascale + TOKENS);            // 32,768 B

  hipLaunchKernelGGL(quant_rows, dim3(TOKENS), dim3(256), 0, stream,
                     x, (int*)xq, ascale, rsum);
  hipLaunchKernelGGL(wconv, dim3((DOUT * DIN / 4) / 256), dim3(256), 0, stream,
                     w, (int*)w8);
  hipLaunchKernelGGL(gemm_i8, dim3((TOKENS / 256) * (DOUT / 256)), dim3(512), 0, stream,
                     xq, w8, ascale, rsum, wscale, woff, bias, y);
}